// Round 1
// baseline (1203.469 us; speedup 1.0000x reference)
//
#include <hip/hip_runtime.h>
#include <hip/hip_bf16.h>

// Problem constants
#define B_  2
#define S_  2048
#define D_  1024
#define V_  32000
#define BS_ 4096          // B*S rows

typedef __attribute__((ext_vector_type(4))) float f32x4;
typedef __attribute__((ext_vector_type(8))) short short8;
typedef unsigned long long u64;
typedef unsigned short u16;

__device__ __forceinline__ u16 f2bf(float x) {           // RNE f32->bf16
  unsigned int u = __float_as_uint(x);
  u += 0x7FFFu + ((u >> 16) & 1u);
  return (u16)(u >> 16);
}
__device__ __forceinline__ u64 pack4bf(float a, float b, float c, float d) {
  return (u64)f2bf(a) | ((u64)f2bf(b) << 16) | ((u64)f2bf(c) << 32) | ((u64)f2bf(d) << 48);
}

// ---------------------------------------------------------------------------
// Generic bf16 GEMM, m97 structure: 128x128 tile, BK=64, 4 waves (2x2),
// global_load_lds width-16 staging, 2 barriers per K-step, 16x16x32 MFMA.
// A [M][K] bf16 row-major, Bt [N][K] bf16 row-major (i.e. B transposed).
// ---------------------------------------------------------------------------
#define GLOAD_LDS16(g, l) __builtin_amdgcn_global_load_lds( \
    (const __attribute__((address_space(1))) void*)(g),     \
    (__attribute__((address_space(3))) void*)(l), 16, 0, 0)

template<bool RELU, bool BF16OUT, bool HASBIAS>
__global__ __launch_bounds__(256) void gemm_bt(
    const u16* __restrict__ A, const u16* __restrict__ Bt,
    const float* __restrict__ bias, void* __restrict__ Cout,
    int M, int N, int K)
{
  __shared__ __attribute__((aligned(16))) u16 Alds[128 * 64];
  __shared__ __attribute__((aligned(16))) u16 Blds[128 * 64];
  const int tid = threadIdx.x;
  const int w = tid >> 6, l = tid & 63;
  const int wr = w >> 1, wc = w & 1;          // 2x2 wave grid, each wave 64x64
  const int m0 = blockIdx.y * 128, n0 = blockIdx.x * 128;
  const int lr = l >> 3, lc = l & 7;          // staging: 8 lanes/row, 8 chunks of 16B
  const int fr = l & 15, fq = l >> 4;         // fragment lane split

  const u16* Ag = A + (size_t)(m0 + w * 8 + lr) * K + lc * 8;
  const u16* Bg = Bt + (size_t)(n0 + w * 8 + lr) * K + lc * 8;

  f32x4 acc[4][4];
#pragma unroll
  for (int i = 0; i < 4; ++i)
#pragma unroll
    for (int j = 0; j < 4; ++j) acc[i][j] = {0.f, 0.f, 0.f, 0.f};

  for (int kt = 0; kt < K; kt += 64) {
    // stage A and B tiles: per round, each wave loads 8 rows (64 lanes x 16B)
#pragma unroll
    for (int r = 0; r < 4; ++r) {
      GLOAD_LDS16(Ag + (size_t)(r * 32) * K + kt, &Alds[(r * 32 + w * 8) * 64]);
      GLOAD_LDS16(Bg + (size_t)(r * 32) * K + kt, &Blds[(r * 32 + w * 8) * 64]);
    }
    __syncthreads();   // drains vmcnt(0) -> LDS tiles visible
#pragma unroll
    for (int ks = 0; ks < 2; ++ks) {
      short8 af[4], bfv[4];
#pragma unroll
      for (int i = 0; i < 4; ++i)
        af[i] = *reinterpret_cast<const short8*>(
            &Alds[(wr * 64 + i * 16 + fr) * 64 + ks * 32 + fq * 8]);
#pragma unroll
      for (int j = 0; j < 4; ++j)
        bfv[j] = *reinterpret_cast<const short8*>(
            &Blds[(wc * 64 + j * 16 + fr) * 64 + ks * 32 + fq * 8]);
#pragma unroll
      for (int i = 0; i < 4; ++i)
#pragma unroll
        for (int j = 0; j < 4; ++j)
          acc[i][j] = __builtin_amdgcn_mfma_f32_16x16x32_bf16(af[i], bfv[j], acc[i][j], 0, 0, 0);
    }
    __syncthreads();
  }

  // epilogue: C/D layout col = lane&15, row = (lane>>4)*4 + reg  [m89/m91]
  const int row0 = m0 + wr * 64 + fq * 4;
  const int col0 = n0 + wc * 64 + fr;
#pragma unroll
  for (int j = 0; j < 4; ++j) {
    const int col = col0 + j * 16;
    const float bv = HASBIAS ? bias[col] : 0.f;
#pragma unroll
    for (int i = 0; i < 4; ++i) {
#pragma unroll
      for (int r = 0; r < 4; ++r) {
        const int row = row0 + i * 16 + r;
        float v = acc[i][j][r] + bv;
        if (RELU) v = fmaxf(v, 0.f);
        if (BF16OUT) ((u16*)Cout)[(size_t)row * N + col] = f2bf(v);
        else         ((float*)Cout)[(size_t)row * N + col] = v;
      }
    }
  }
}

// ---------------------------------------------------------------------------
// Weight prep
// ---------------------------------------------------------------------------
// f32 [K][N] -> bf16 [N][K] (transpose + convert), 32x32 LDS tiles
__global__ __launch_bounds__(256) void transpose_f2b(
    const float* __restrict__ in, u16* __restrict__ out, int K, int N)
{
  __shared__ float t[32][33];
  const int n0 = blockIdx.x * 32, k0 = blockIdx.y * 32;
  const int r = threadIdx.x >> 5, cc = threadIdx.x & 31;
#pragma unroll
  for (int rr = 0; rr < 4; ++rr) {
    const int ki = rr * 8 + r;
    t[ki][cc] = in[(size_t)(k0 + ki) * N + n0 + cc];
  }
  __syncthreads();
#pragma unroll
  for (int rr = 0; rr < 4; ++rr) {
    const int ni = rr * 8 + r;
    out[(size_t)(n0 + ni) * K + k0 + cc] = f2bf(t[cc][ni]);
  }
}

// conv_w [O][I][3] f32 -> Bt_conv [O][k*D + i] bf16 (im2col weight layout)
__global__ __launch_bounds__(256) void convw_reorder(
    const float* __restrict__ cw, u16* __restrict__ out)
{
  const int gid = blockIdx.x * 256 + threadIdx.x;   // o*D + i
  const int o = gid >> 10, i = gid & 1023;
  const float w0 = cw[(size_t)gid * 3 + 0];
  const float w1 = cw[(size_t)gid * 3 + 1];
  const float w2 = cw[(size_t)gid * 3 + 2];
  out[(size_t)o * 3072 + i]          = f2bf(w0);
  out[(size_t)o * 3072 + 1024 + i]   = f2bf(w1);
  out[(size_t)o * 3072 + 2048 + i]   = f2bf(w2);
}

// embedding gather -> bf16 A for GEMM1
__global__ __launch_bounds__(256) void gather_emb(
    const int* __restrict__ X, const float* __restrict__ emb, u16* __restrict__ xb)
{
  const int row = blockIdx.x;
  const int tok = X[row];
  const int d4 = threadIdx.x * 4;
  const float4 v = *reinterpret_cast<const float4*>(emb + (size_t)tok * D_ + d4);
  *(u64*)(&xb[(size_t)row * D_ + d4]) = pack4bf(v.x, v.y, v.z, v.w);
}

// ---------------------------------------------------------------------------
// minGRU scan: h_t = (1-z)h_{t-1} + z*g(hid), z = sigmoid(gate)
// 3-pass chunked linear recurrence: 64 chunks x 32 steps, block = (b, chunk),
// 256 threads x 4 channels (float4 coalesced over D).
// ---------------------------------------------------------------------------
#define GRU_CP(hid_, gate_, h_, cp_) {                                   \
  const float t_ = __expf(-(gate_));                                     \
  const float z_ = 1.f / (1.f + t_);                                     \
  const float c_ = t_ * z_;                                              \
  const float g_ = ((hid_) >= 0.f) ? ((hid_) + 0.5f)                     \
                                   : (1.f / (1.f + __expf(-(hid_))));    \
  (h_) = c_ * (h_) + z_ * g_; (cp_) *= c_; }

#define GRU_NC(hid_, gate_, h_) {                                        \
  const float t_ = __expf(-(gate_));                                     \
  const float z_ = 1.f / (1.f + t_);                                     \
  const float g_ = ((hid_) >= 0.f) ? ((hid_) + 0.5f)                     \
                                   : (1.f / (1.f + __expf(-(hid_))));    \
  (h_) = (t_ * z_) * (h_) + z_ * g_; }

__global__ __launch_bounds__(256) void scan_partial(
    const float* __restrict__ hg, float* __restrict__ Cb, float* __restrict__ Vb)
{
  const int b = blockIdx.x >> 6, c = blockIdx.x & 63;
  const int d4 = threadIdx.x * 4;
  const float* base = hg + ((size_t)b * S_ + (size_t)c * 32) * (2 * D_);
  float h[4] = {0.f, 0.f, 0.f, 0.f}, cp[4] = {1.f, 1.f, 1.f, 1.f};
  for (int t = 0; t < 32; ++t) {
    const float4 hd = *reinterpret_cast<const float4*>(base + (size_t)t * (2 * D_) + d4);
    const float4 gt = *reinterpret_cast<const float4*>(base + (size_t)t * (2 * D_) + D_ + d4);
    GRU_CP(hd.x, gt.x, h[0], cp[0]); GRU_CP(hd.y, gt.y, h[1], cp[1]);
    GRU_CP(hd.z, gt.z, h[2], cp[2]); GRU_CP(hd.w, gt.w, h[3], cp[3]);
  }
  const size_t o = ((size_t)(b * 64 + c)) * D_ + d4;
  *(float4*)(Cb + o) = make_float4(cp[0], cp[1], cp[2], cp[3]);
  *(float4*)(Vb + o) = make_float4(h[0], h[1], h[2], h[3]);
}

__global__ void scan_carry(const float* __restrict__ Cb, const float* __restrict__ Vb,
                           float* __restrict__ Hs)
{
  const int gid = blockIdx.x * 256 + threadIdx.x;   // 0..2047 = (b,d)
  const int b = gid >> 10, d = gid & 1023;
  float h = 0.f;
  for (int c = 0; c < 64; ++c) {
    const size_t o = ((size_t)(b * 64 + c)) * D_ + d;
    Hs[o] = h;
    h = Cb[o] * h + Vb[o];
  }
}

// pass C: recompute scan with carry-in, fuse LayerNorm + residual + im2col
// scatter (3 shifted bf16 slices of A_conv [BS][3*D]).
__global__ __launch_bounds__(256) void scan_emit(
    const float* __restrict__ hg, const float* __restrict__ Hs,
    const int* __restrict__ X, const float* __restrict__ emb,
    const float* __restrict__ ln_g, const float* __restrict__ ln_b,
    u16* __restrict__ Aconv)
{
  __shared__ float red[4];
  const int b = blockIdx.x >> 6, c = blockIdx.x & 63;
  const int tid = threadIdx.x;
  const int w = tid >> 6, l = tid & 63;
  const int d4 = tid * 4;
  const float* base = hg + ((size_t)b * S_ + (size_t)c * 32) * (2 * D_);
  float h0, h1, h2, h3;
  {
    const float4 hs = *reinterpret_cast<const float4*>(Hs + ((size_t)(b * 64 + c)) * D_ + d4);
    h0 = hs.x; h1 = hs.y; h2 = hs.z; h3 = hs.w;
  }
  const float4 lg = *reinterpret_cast<const float4*>(ln_g + d4);
  const float4 lb = *reinterpret_cast<const float4*>(ln_b + d4);

  for (int t = 0; t < 32; ++t) {
    const int s = c * 32 + t;
    const float4 hd = *reinterpret_cast<const float4*>(base + (size_t)t * (2 * D_) + d4);
    const float4 gt = *reinterpret_cast<const float4*>(base + (size_t)t * (2 * D_) + D_ + d4);
    GRU_NC(hd.x, gt.x, h0); GRU_NC(hd.y, gt.y, h1);
    GRU_NC(hd.z, gt.z, h2); GRU_NC(hd.w, gt.w, h3);

    // block LN over D=1024 (two-pass for variance accuracy)
    float sm = h0 + h1 + h2 + h3;
#pragma unroll
    for (int m = 1; m < 64; m <<= 1) sm += __shfl_xor(sm, m);
    __syncthreads();
    if (l == 0) red[w] = sm;
    __syncthreads();
    const float mu = (red[0] + red[1] + red[2] + red[3]) * (1.f / (float)D_);
    float q = (h0 - mu) * (h0 - mu) + (h1 - mu) * (h1 - mu) +
              (h2 - mu) * (h2 - mu) + (h3 - mu) * (h3 - mu);
#pragma unroll
    for (int m = 1; m < 64; m <<= 1) q += __shfl_xor(q, m);
    __syncthreads();
    if (l == 0) red[w] = q;
    __syncthreads();
    const float var = (red[0] + red[1] + red[2] + red[3]) * (1.f / (float)D_);
    const float rstd = rsqrtf(var + 1e-5f);

    const int tok = X[b * S_ + s];
    const float4 e = *reinterpret_cast<const float4*>(emb + (size_t)tok * D_ + d4);
    const float x0 = (h0 - mu) * rstd * lg.x + lb.x + e.x;
    const float x1 = (h1 - mu) * rstd * lg.y + lb.y + e.y;
    const float x2 = (h2 - mu) * rstd * lg.z + lb.z + e.z;
    const float x3 = (h3 - mu) * rstd * lg.w + lb.w + e.w;
    const u64 pk = pack4bf(x0, x1, x2, x3);

    const size_t row = (size_t)b * S_ + s;
    *(u64*)(&Aconv[row * 3072 + D_ + d4]) = pk;                        // slice k=1, row s
    if (s + 1 < S_) *(u64*)(&Aconv[(row + 1) * 3072 + d4]) = pk;       // slice k=0, row s+1
    if (s > 0)      *(u64*)(&Aconv[(row - 1) * 3072 + 2 * D_ + d4]) = pk; // k=2, row s-1
    if (s == 0)       *(u64*)(&Aconv[row * 3072 + d4]) = 0ull;         // left pad
    if (s == S_ - 1)  *(u64*)(&Aconv[row * 3072 + 2 * D_ + d4]) = 0ull;// right pad
  }
}

// ---------------------------------------------------------------------------
// BatchNorm (training stats over B*S rows per channel), deterministic 2-stage
// ---------------------------------------------------------------------------
__global__ __launch_bounds__(256) void bn_partial(
    const float* __restrict__ cv, float* __restrict__ ps, float* __restrict__ pq)
{
  const int blk = blockIdx.x;          // 64 blocks x 64 rows
  const int c4 = threadIdx.x * 4;
  float s0 = 0, s1 = 0, s2 = 0, s3 = 0, q0 = 0, q1 = 0, q2 = 0, q3 = 0;
  for (int r = 0; r < 64; ++r) {
    const float4 v = *reinterpret_cast<const float4*>(cv + ((size_t)blk * 64 + r) * D_ + c4);
    s0 += v.x; s1 += v.y; s2 += v.z; s3 += v.w;
    q0 += v.x * v.x; q1 += v.y * v.y; q2 += v.z * v.z; q3 += v.w * v.w;
  }
  *(float4*)(ps + (size_t)blk * D_ + c4) = make_float4(s0, s1, s2, s3);
  *(float4*)(pq + (size_t)blk * D_ + c4) = make_float4(q0, q1, q2, q3);
}

__global__ void bn_finalize(const float* __restrict__ ps, const float* __restrict__ pq,
                            const float* __restrict__ bn_g, const float* __restrict__ bn_b,
                            float* __restrict__ scale, float* __restrict__ shift)
{
  const int c = blockIdx.x * 256 + threadIdx.x;  // 1024 channels
  float s = 0.f, q = 0.f;
  for (int blk = 0; blk < 64; ++blk) { s += ps[(size_t)blk * D_ + c]; q += pq[(size_t)blk * D_ + c]; }
  const float m = s * (1.f / (float)BS_);
  const float var = q * (1.f / (float)BS_) - m * m;
  const float rs = rsqrtf(var + 1e-5f);
  const float sc = bn_g[c] * rs;
  scale[c] = sc;
  shift[c] = bn_b[c] - m * sc;
}

__global__ __launch_bounds__(256) void bn_apply(
    const float* __restrict__ cv, const float* __restrict__ scale,
    const float* __restrict__ shift, u16* __restrict__ out)
{
  const size_t idx = ((size_t)blockIdx.x * 256 + threadIdx.x) * 4;
  const int c = (int)(idx & 1023);
  const float4 v = *reinterpret_cast<const float4*>(cv + idx);
  const float4 sc = *reinterpret_cast<const float4*>(scale + c);
  const float4 sh = *reinterpret_cast<const float4*>(shift + c);
  *(u64*)(&out[idx]) = pack4bf(v.x * sc.x + sh.x, v.y * sc.y + sh.y,
                               v.z * sc.z + sh.z, v.w * sc.w + sh.w);
}

// ---------------------------------------------------------------------------
extern "C" void kernel_launch(void* const* d_in, const int* in_sizes, int n_in,
                              void* d_out, int out_size, void* d_ws, size_t ws_size,
                              hipStream_t stream)
{
  const int*   X      = (const int*)d_in[0];
  const float* emb    = (const float*)d_in[1];
  const float* w_hg   = (const float*)d_in[2];
  const float* conv_w = (const float*)d_in[3];
  // d_in[4] = conv_b: exactly cancelled by training-mode BN (mean-subtract)
  const float* bn_g   = (const float*)d_in[5];
  const float* bn_b   = (const float*)d_in[6];
  const float* ln_g   = (const float*)d_in[7];
  const float* ln_b   = (const float*)d_in[8];
  const float* w1     = (const float*)d_in[9];
  const float* b1     = (const float*)d_in[10];
  const float* w2     = (const float*)d_in[11];
  const float* b2     = (const float*)d_in[12];
  const float* w3     = (const float*)d_in[13];
  const float* b3     = (const float*)d_in[14];
  float* out = (float*)d_out;
  char* ws = (char*)d_ws;

  // Workspace layout (~151 MB). W3T (written LAST, after GEMM3) overlays every
  // buffer that is dead by then; A4 (live into GEMM4) sits in front.
  const size_t OFF_A4    = 0;                        // 16,777,216  bf16 [4096][2048]
  const size_t BASE      = 16777216;
  const size_t OFF_W3T   = BASE;                     // 131,072,000 bf16 [32000][2048]
  const size_t OFF_WHGT  = BASE;                     //   4,194,304 bf16 [2048][1024]
  const size_t OFF_W1T   = BASE + 4194304;           //   4,194,304 bf16 [2048][1024]
  const size_t OFF_W2T   = OFF_W1T + 4194304;        //   8,388,608 bf16 [2048][2048]
  const size_t OFF_WCVT  = OFF_W2T + 8388608;        //   6,291,456 bf16 [1024][3072]
  const size_t OFF_XBF   = OFF_WCVT + 6291456;       //   8,388,608 bf16 [4096][1024]
  const size_t OFF_HG    = OFF_XBF + 8388608;        //  33,554,432 f32  [4096][2048]
  const size_t OFF_CB    = OFF_HG + 33554432;        //     524,288 f32  [2][64][1024]
  const size_t OFF_VB    = OFF_CB + 524288;
  const size_t OFF_HS    = OFF_VB + 524288;
  const size_t OFF_ACONV = OFF_HS + 524288;          //  25,165,824 bf16 [4096][3072]
  const size_t OFF_CVO   = OFF_ACONV + 25165824;     //  16,777,216 f32  [4096][1024]
  const size_t OFF_A2    = OFF_CVO + 16777216;       //   8,388,608 bf16 [4096][1024]
  const size_t OFF_A3    = OFF_A2 + 8388608;         //  16,777,216 bf16 [4096][2048]
  const size_t OFF_BNS   = OFF_A3 + 16777216;        //     262,144
  const size_t OFF_BNQ   = OFF_BNS + 262144;
  const size_t OFF_SC    = OFF_BNQ + 262144;
  const size_t OFF_SH    = OFF_SC + 4096;
  (void)in_sizes; (void)n_in; (void)out_size; (void)ws_size; (void)OFF_SH;

  u16*   WHGT = (u16*)(ws + OFF_WHGT);
  u16*   W1T  = (u16*)(ws + OFF_W1T);
  u16*   W2T  = (u16*)(ws + OFF_W2T);
  u16*   W3T  = (u16*)(ws + OFF_W3T);
  u16*   WCVT = (u16*)(ws + OFF_WCVT);
  u16*   XBF  = (u16*)(ws + OFF_XBF);
  float* HG   = (float*)(ws + OFF_HG);
  float* CB   = (float*)(ws + OFF_CB);
  float* VB   = (float*)(ws + OFF_VB);
  float* HS   = (float*)(ws + OFF_HS);
  u16*   ACONV= (u16*)(ws + OFF_ACONV);
  float* CVO  = (float*)(ws + OFF_CVO);
  u16*   A2   = (u16*)(ws + OFF_A2);
  u16*   A3   = (u16*)(ws + OFF_A3);
  u16*   A4   = (u16*)(ws + OFF_A4);
  float* BNS  = (float*)(ws + OFF_BNS);
  float* BNQ  = (float*)(ws + OFF_BNQ);
  float* SC   = (float*)(ws + OFF_SC);
  float* SH   = (float*)(ws + OFF_SH);

  // --- weight prep (small ones now; w3 later so its region can be reused) ---
  transpose_f2b<<<dim3(2048 / 32, 1024 / 32), 256, 0, stream>>>(w_hg, WHGT, 1024, 2048);
  transpose_f2b<<<dim3(2048 / 32, 1024 / 32), 256, 0, stream>>>(w1,   W1T,  1024, 2048);
  transpose_f2b<<<dim3(2048 / 32, 2048 / 32), 256, 0, stream>>>(w2,   W2T,  2048, 2048);
  convw_reorder<<<4096, 256, 0, stream>>>(conv_w, WCVT);

  // --- embedding gather ---
  gather_emb<<<BS_, 256, 0, stream>>>(X, emb, XBF);

  // --- GEMM1: hg = x @ w_hg  [4096x1024]@[1024x2048] -> f32 ---
  gemm_bt<false, false, false><<<dim3(2048 / 128, BS_ / 128), 256, 0, stream>>>(
      XBF, WHGT, nullptr, HG, BS_, 2048, 1024);

  // --- minGRU chunked scan + fused LN/residual/im2col ---
  scan_partial<<<B_ * 64, 256, 0, stream>>>(HG, CB, VB);
  scan_carry<<<8, 256, 0, stream>>>(CB, VB, HS);
  scan_emit<<<B_ * 64, 256, 0, stream>>>(HG, HS, X, emb, ln_g, ln_b, ACONV);

  // --- conv1d as GEMM: [4096x3072]@[3072x1024] -> f32 ---
  gemm_bt<false, false, false><<<dim3(1024 / 128, BS_ / 128), 256, 0, stream>>>(
      ACONV, WCVT, nullptr, CVO, BS_, 1024, 3072);

  // --- BatchNorm ---
  bn_partial<<<64, 256, 0, stream>>>(CVO, BNS, BNQ);
  bn_finalize<<<4, 256, 0, stream>>>(BNS, BNQ, bn_g, bn_b, SC, SH);
  bn_apply<<<4096, 256, 0, stream>>>(CVO, SC, SH, A2);

  // --- MLP ---
  gemm_bt<true, true, true><<<dim3(2048 / 128, BS_ / 128), 256, 0, stream>>>(
      A2, W1T, b1, A3, BS_, 2048, 1024);
  gemm_bt<true, true, true><<<dim3(2048 / 128, BS_ / 128), 256, 0, stream>>>(
      A3, W2T, b2, A4, BS_, 2048, 2048);

  // --- w3 transpose now (its region's aliases are all dead) + final GEMM ---
  transpose_f2b<<<dim3(V_ / 32, 2048 / 32), 256, 0, stream>>>(w3, W3T, 2048, V_);
  gemm_bt<false, false, true><<<dim3(V_ / 128, BS_ / 128), 256, 0, stream>>>(
      A4, W3T, b3, out, BS_, V_, 2048);
}

// Round 2
// 931.802 us; speedup vs baseline: 1.2916x; 1.2916x over previous
//
#include <hip/hip_runtime.h>
#include <hip/hip_bf16.h>

// Problem constants
#define B_  2
#define S_  2048
#define D_  1024
#define V_  32000
#define BS_ 4096          // B*S rows

typedef __attribute__((ext_vector_type(4))) float f32x4;
typedef __attribute__((ext_vector_type(8))) short short8;
typedef unsigned long long u64;
typedef unsigned short u16;

__device__ __forceinline__ u16 f2bf(float x) {           // RNE f32->bf16
  unsigned int u = __float_as_uint(x);
  u += 0x7FFFu + ((u >> 16) & 1u);
  return (u16)(u >> 16);
}
__device__ __forceinline__ u64 pack4bf(float a, float b, float c, float d) {
  return (u64)f2bf(a) | ((u64)f2bf(b) << 16) | ((u64)f2bf(c) << 32) | ((u64)f2bf(d) << 48);
}

#define GLOAD_LDS16(g, l) __builtin_amdgcn_global_load_lds( \
    (const __attribute__((address_space(1))) void*)(g),     \
    (__attribute__((address_space(3))) void*)(l), 16, 0, 0)

// ---------------------------------------------------------------------------
// 128x128 m97-structure GEMM (kept for the small GEMMs)
// ---------------------------------------------------------------------------
template<bool RELU, bool BF16OUT, bool HASBIAS>
__global__ __launch_bounds__(256) void gemm_bt(
    const u16* __restrict__ A, const u16* __restrict__ Bt,
    const float* __restrict__ bias, void* __restrict__ Cout,
    int M, int N, int K)
{
  __shared__ __attribute__((aligned(16))) u16 Alds[128 * 64];
  __shared__ __attribute__((aligned(16))) u16 Blds[128 * 64];
  const int tid = threadIdx.x;
  const int w = tid >> 6, l = tid & 63;
  const int wr = w >> 1, wc = w & 1;
  const int m0 = blockIdx.y * 128, n0 = blockIdx.x * 128;
  const int lr = l >> 3, lc = l & 7;
  const int fr = l & 15, fq = l >> 4;

  const u16* Ag = A + (size_t)(m0 + w * 8 + lr) * K + lc * 8;
  const u16* Bg = Bt + (size_t)(n0 + w * 8 + lr) * K + lc * 8;

  f32x4 acc[4][4];
#pragma unroll
  for (int i = 0; i < 4; ++i)
#pragma unroll
    for (int j = 0; j < 4; ++j) acc[i][j] = {0.f, 0.f, 0.f, 0.f};

  for (int kt = 0; kt < K; kt += 64) {
#pragma unroll
    for (int r = 0; r < 4; ++r) {
      GLOAD_LDS16(Ag + (size_t)(r * 32) * K + kt, &Alds[(r * 32 + w * 8) * 64]);
      GLOAD_LDS16(Bg + (size_t)(r * 32) * K + kt, &Blds[(r * 32 + w * 8) * 64]);
    }
    __syncthreads();
#pragma unroll
    for (int ks = 0; ks < 2; ++ks) {
      short8 af[4], bfv[4];
#pragma unroll
      for (int i = 0; i < 4; ++i)
        af[i] = *reinterpret_cast<const short8*>(
            &Alds[(wr * 64 + i * 16 + fr) * 64 + ks * 32 + fq * 8]);
#pragma unroll
      for (int j = 0; j < 4; ++j)
        bfv[j] = *reinterpret_cast<const short8*>(
            &Blds[(wc * 64 + j * 16 + fr) * 64 + ks * 32 + fq * 8]);
#pragma unroll
      for (int i = 0; i < 4; ++i)
#pragma unroll
        for (int j = 0; j < 4; ++j)
          acc[i][j] = __builtin_amdgcn_mfma_f32_16x16x32_bf16(af[i], bfv[j], acc[i][j], 0, 0, 0);
    }
    __syncthreads();
  }

  const int row0 = m0 + wr * 64 + fq * 4;
  const int col0 = n0 + wc * 64 + fr;
#pragma unroll
  for (int j = 0; j < 4; ++j) {
    const int col = col0 + j * 16;
    const float bv = HASBIAS ? bias[col] : 0.f;
#pragma unroll
    for (int i = 0; i < 4; ++i) {
#pragma unroll
      for (int r = 0; r < 4; ++r) {
        const int row = row0 + i * 16 + r;
        float v = acc[i][j][r] + bv;
        if (RELU) v = fmaxf(v, 0.f);
        if (BF16OUT) ((u16*)Cout)[(size_t)row * N + col] = f2bf(v);
        else         ((float*)Cout)[(size_t)row * N + col] = v;
      }
    }
  }
}

// ---------------------------------------------------------------------------
// 256x256 8-phase GEMM (T2 swizzle + T3/T4 counted-vmcnt pipeline + T5).
// 512 thr = 8 waves (2M x 4N); BK=64; LDS 128KB dbuf; 4 phases/K-tile.
// A [M][K] bf16, Bt [N][K] bf16. Flat grid, chunk-rasterized (CW n-tiles).
// ---------------------------------------------------------------------------
#define AOFF(b, h) (((b) * 4 + (h)) * 8192)
#define BOFF(b, h) (((b) * 4 + 2 + (h)) * 8192)
#define FENCE() asm volatile("" ::: "memory")
#define BARRIER() do { FENCE(); __builtin_amdgcn_s_barrier(); FENCE(); } while (0)
#define WAIT_LGKM0() asm volatile("s_waitcnt lgkmcnt(0)" ::: "memory")

template<bool RELU, bool BF16OUT, bool HASBIAS>
__global__ __launch_bounds__(512, 2) void gemm256_bt(
    const u16* __restrict__ A, const u16* __restrict__ Bt,
    const float* __restrict__ bias, void* __restrict__ Cout,
    int M, int N, int K, int CW)
{
  __shared__ __attribute__((aligned(16))) u16 LDS[65536];
  const int tid = threadIdx.x;
  const int w = tid >> 6, l = tid & 63;
  const int wr = w >> 2, wc = w & 3;          // 2 x 4 wave grid; wave owns 128x64
  const int fr = l & 15, fq = l >> 4;

  // chunk rasterization: CW n-tiles x all m-tiles per chunk (m fastest)
  const int MTt = M >> 8;
  const int bpc = MTt * CW;
  const int chunk = blockIdx.x / bpc, rem = blockIdx.x % bpc;
  const int m0 = (rem % MTt) << 8;
  const int n0 = ((chunk * CW) + rem / MTt) << 8;

  const int NT = K >> 6;
  const u16* Abase = A + (size_t)m0 * K;
  const u16* Bbase = Bt + (size_t)n0 * K;

  // staging lane geometry (loop-invariant): granule G = w*128 + q*64 + l,
  // row r = G>>3, src granule g = (l&7) ^ (r&7)  [XOR swizzle, both sides]
  const int rq_[2] = { w * 16 + (l >> 3), w * 16 + 8 + (l >> 3) };
  const int gq_[2] = { (l & 7) ^ (rq_[0] & 7), (l & 7) ^ (rq_[1] & 7) };

#define STAGE_HALF(matbase, h, t, ldsoff) do {                               \
  _Pragma("unroll")                                                          \
  for (int q_ = 0; q_ < 2; ++q_)                                             \
    GLOAD_LDS16((matbase) + ((size_t)((h) * 128 + rq_[q_])) * K +            \
                    (size_t)(t) * 64 + gq_[q_] * 8,                          \
                &LDS[(ldsoff) + (w * 128 + q_ * 64) * 8]);                   \
} while (0)

#define READ_A(arr, bufb, q_) do {                                           \
  _Pragma("unroll")                                                          \
  for (int i_ = 0; i_ < 4; ++i_) {                                           \
    const int r_ = (q_) * 64 + i_ * 16 + fr;                                 \
    _Pragma("unroll")                                                        \
    for (int ks_ = 0; ks_ < 2; ++ks_)                                        \
      arr[i_][ks_] = *reinterpret_cast<const short8*>(                       \
          &LDS[AOFF(bufb, wr) + r_ * 64 + ((ks_ * 4 + fq) ^ (fr & 7)) * 8]); \
  } } while (0)

#define READ_B(arr, bufb, jq_) do {                                          \
  _Pragma("unroll")                                                          \
  for (int j_ = 0; j_ < 2; ++j_) {                                           \
    const int r_ = (wc & 1) * 64 + (jq_) * 32 + j_ * 16 + fr;                \
    _Pragma("unroll")                                                        \
    for (int ks_ = 0; ks_ < 2; ++ks_)                                        \
      arr[j_][ks_] = *reinterpret_cast<const short8*>(                       \
          &LDS[BOFF(bufb, wc >> 1) + r_ * 64 +                               \
               ((ks_ * 4 + fq) ^ (fr & 7)) * 8]);                            \
  } } while (0)

#define MFMA_Q(arrA, arrB, itb, jtb) do {                                    \
  _Pragma("unroll")                                                          \
  for (int i_ = 0; i_ < 4; ++i_)                                             \
    _Pragma("unroll")                                                        \
    for (int j_ = 0; j_ < 2; ++j_)                                           \
      _Pragma("unroll")                                                      \
      for (int ks_ = 0; ks_ < 2; ++ks_)                                      \
        acc[(itb) + i_][(jtb) + j_] = __builtin_amdgcn_mfma_f32_16x16x32_bf16( \
            arrA[i_][ks_], arrB[j_][ks_], acc[(itb) + i_][(jtb) + j_], 0, 0, 0); \
} while (0)

  f32x4 acc[8][4];
#pragma unroll
  for (int i = 0; i < 8; ++i)
#pragma unroll
    for (int j = 0; j < 4; ++j) acc[i][j] = {0.f, 0.f, 0.f, 0.f};

  // prologue: full tile 0, then BH0(1), AH0(1)  (steady-state slot pattern)
  STAGE_HALF(Abase, 0, 0, AOFF(0, 0));
  STAGE_HALF(Abase, 1, 0, AOFF(0, 1));
  STAGE_HALF(Bbase, 0, 0, BOFF(0, 0));
  STAGE_HALF(Bbase, 1, 0, BOFF(0, 1));
  if (NT > 1) {
    STAGE_HALF(Bbase, 0, 1, BOFF(1, 0));
    STAGE_HALF(Abase, 0, 1, AOFF(1, 0));
    asm volatile("s_waitcnt vmcnt(4)" ::: "memory");
  } else {
    asm volatile("s_waitcnt vmcnt(0)" ::: "memory");
  }
  BARRIER();

  for (int t = 0; t < NT; ++t) {
    const int cb = t & 1, nb = cb ^ 1;
    short8 a0[4][2], a1[4][2], b0[2][2], b1[2][2];

    // P1: read a0,b0 (12 ds_read); stage AH1(t+1); MFMA quad (0,0)
    READ_A(a0, cb, 0);
    READ_B(b0, cb, 0);
    if (t + 1 < NT) STAGE_HALF(Abase, 1, t + 1, AOFF(nb, 1));
    BARRIER(); WAIT_LGKM0();
    __builtin_amdgcn_s_setprio(1);
    MFMA_Q(a0, b0, 0, 0);
    __builtin_amdgcn_s_setprio(0);
    BARRIER();

    // P2: read b1 (4); stage BH1(t+1); quad (0,2)
    READ_B(b1, cb, 1);
    if (t + 1 < NT) STAGE_HALF(Bbase, 1, t + 1, BOFF(nb, 1));
    BARRIER(); WAIT_LGKM0();
    __builtin_amdgcn_s_setprio(1);
    MFMA_Q(a0, b1, 0, 2);
    __builtin_amdgcn_s_setprio(0);
    BARRIER();

    // P3: read a1 (8); stage BH0(t+2); quad (4,2)
    READ_A(a1, cb, 1);
    if (t + 2 < NT) STAGE_HALF(Bbase, 0, t + 2, BOFF(cb, 0));
    BARRIER(); WAIT_LGKM0();
    __builtin_amdgcn_s_setprio(1);
    MFMA_Q(a1, b1, 4, 2);
    __builtin_amdgcn_s_setprio(0);
    BARRIER();

    // P4: stage AH0(t+2); quad (4,0); counted vmcnt at tile boundary
    if (t + 2 < NT) STAGE_HALF(Abase, 0, t + 2, AOFF(cb, 0));
    BARRIER(); WAIT_LGKM0();
    __builtin_amdgcn_s_setprio(1);
    MFMA_Q(a1, b0, 4, 0);
    __builtin_amdgcn_s_setprio(0);
    if (t + 2 < NT) { asm volatile("s_waitcnt vmcnt(4)" ::: "memory"); }
    else            { asm volatile("s_waitcnt vmcnt(0)" ::: "memory"); }
    BARRIER();
  }

  // epilogue: C/D layout col = lane&15, row = (lane>>4)*4 + reg
  const int row0 = m0 + wr * 128 + fq * 4;
  const int col0 = n0 + wc * 64 + fr;
#pragma unroll
  for (int jt = 0; jt < 4; ++jt) {
    const int col = col0 + jt * 16;
    const float bv = HASBIAS ? bias[col] : 0.f;
#pragma unroll
    for (int it = 0; it < 8; ++it) {
#pragma unroll
      for (int rr = 0; rr < 4; ++rr) {
        const int row = row0 + it * 16 + rr;
        float v = acc[it][jt][rr] + bv;
        if (RELU) v = fmaxf(v, 0.f);
        if (BF16OUT) ((u16*)Cout)[(size_t)row * N + col] = f2bf(v);
        else         ((float*)Cout)[(size_t)row * N + col] = v;
      }
    }
  }
#undef STAGE_HALF
#undef READ_A
#undef READ_B
#undef MFMA_Q
}

// ---------------------------------------------------------------------------
// Weight prep
// ---------------------------------------------------------------------------
__global__ __launch_bounds__(256) void transpose_f2b(
    const float* __restrict__ in, u16* __restrict__ out, int K, int N)
{
  __shared__ float t[32][33];
  const int n0 = blockIdx.x * 32, k0 = blockIdx.y * 32;
  const int r = threadIdx.x >> 5, cc = threadIdx.x & 31;
#pragma unroll
  for (int rr = 0; rr < 4; ++rr) {
    const int ki = rr * 8 + r;
    t[ki][cc] = in[(size_t)(k0 + ki) * N + n0 + cc];
  }
  __syncthreads();
#pragma unroll
  for (int rr = 0; rr < 4; ++rr) {
    const int ni = rr * 8 + r;
    out[(size_t)(n0 + ni) * K + k0 + cc] = f2bf(t[cc][ni]);
  }
}

__global__ __launch_bounds__(256) void convw_reorder(
    const float* __restrict__ cw, u16* __restrict__ out)
{
  const int gid = blockIdx.x * 256 + threadIdx.x;   // o*D + i
  const int o = gid >> 10, i = gid & 1023;
  const float w0 = cw[(size_t)gid * 3 + 0];
  const float w1 = cw[(size_t)gid * 3 + 1];
  const float w2 = cw[(size_t)gid * 3 + 2];
  out[(size_t)o * 3072 + i]          = f2bf(w0);
  out[(size_t)o * 3072 + 1024 + i]   = f2bf(w1);
  out[(size_t)o * 3072 + 2048 + i]   = f2bf(w2);
}

__global__ __launch_bounds__(256) void gather_emb(
    const int* __restrict__ X, const float* __restrict__ emb, u16* __restrict__ xb)
{
  const int row = blockIdx.x;
  const int tok = X[row];
  const int d4 = threadIdx.x * 4;
  const float4 v = *reinterpret_cast<const float4*>(emb + (size_t)tok * D_ + d4);
  *(u64*)(&xb[(size_t)row * D_ + d4]) = pack4bf(v.x, v.y, v.z, v.w);
}

// ---------------------------------------------------------------------------
// minGRU scan (3-pass chunked linear recurrence)
// ---------------------------------------------------------------------------
#define GRU_CP(hid_, gate_, h_, cp_) {                                   \
  const float t_ = __expf(-(gate_));                                     \
  const float z_ = 1.f / (1.f + t_);                                     \
  const float c_ = t_ * z_;                                              \
  const float g_ = ((hid_) >= 0.f) ? ((hid_) + 0.5f)                     \
                                   : (1.f / (1.f + __expf(-(hid_))));    \
  (h_) = c_ * (h_) + z_ * g_; (cp_) *= c_; }

#define GRU_NC(hid_, gate_, h_) {                                        \
  const float t_ = __expf(-(gate_));                                     \
  const float z_ = 1.f / (1.f + t_);                                     \
  const float g_ = ((hid_) >= 0.f) ? ((hid_) + 0.5f)                     \
                                   : (1.f / (1.f + __expf(-(hid_))));    \
  (h_) = (t_ * z_) * (h_) + z_ * g_; }

__global__ __launch_bounds__(256) void scan_partial(
    const float* __restrict__ hg, float* __restrict__ Cb, float* __restrict__ Vb)
{
  const int b = blockIdx.x >> 6, c = blockIdx.x & 63;
  const int d4 = threadIdx.x * 4;
  const float* base = hg + ((size_t)b * S_ + (size_t)c * 32) * (2 * D_);
  float h[4] = {0.f, 0.f, 0.f, 0.f}, cp[4] = {1.f, 1.f, 1.f, 1.f};
  for (int t = 0; t < 32; ++t) {
    const float4 hd = *reinterpret_cast<const float4*>(base + (size_t)t * (2 * D_) + d4);
    const float4 gt = *reinterpret_cast<const float4*>(base + (size_t)t * (2 * D_) + D_ + d4);
    GRU_CP(hd.x, gt.x, h[0], cp[0]); GRU_CP(hd.y, gt.y, h[1], cp[1]);
    GRU_CP(hd.z, gt.z, h[2], cp[2]); GRU_CP(hd.w, gt.w, h[3], cp[3]);
  }
  const size_t o = ((size_t)(b * 64 + c)) * D_ + d4;
  *(float4*)(Cb + o) = make_float4(cp[0], cp[1], cp[2], cp[3]);
  *(float4*)(Vb + o) = make_float4(h[0], h[1], h[2], h[3]);
}

__global__ void scan_carry(const float* __restrict__ Cb, const float* __restrict__ Vb,
                           float* __restrict__ Hs)
{
  const int gid = blockIdx.x * 256 + threadIdx.x;   // 0..2047 = (b,d)
  const int b = gid >> 10, d = gid & 1023;
  float h = 0.f;
  for (int c = 0; c < 64; ++c) {
    const size_t o = ((size_t)(b * 64 + c)) * D_ + d;
    Hs[o] = h;
    h = Cb[o] * h + Vb[o];
  }
}

__global__ __launch_bounds__(256) void scan_emit(
    const float* __restrict__ hg, const float* __restrict__ Hs,
    const int* __restrict__ X, const float* __restrict__ emb,
    const float* __restrict__ ln_g, const float* __restrict__ ln_b,
    u16* __restrict__ Aconv)
{
  __shared__ float red[4];
  const int b = blockIdx.x >> 6, c = blockIdx.x & 63;
  const int tid = threadIdx.x;
  const int w = tid >> 6, l = tid & 63;
  const int d4 = tid * 4;
  const float* base = hg + ((size_t)b * S_ + (size_t)c * 32) * (2 * D_);
  float h0, h1, h2, h3;
  {
    const float4 hs = *reinterpret_cast<const float4*>(Hs + ((size_t)(b * 64 + c)) * D_ + d4);
    h0 = hs.x; h1 = hs.y; h2 = hs.z; h3 = hs.w;
  }
  const float4 lg = *reinterpret_cast<const float4*>(ln_g + d4);
  const float4 lb = *reinterpret_cast<const float4*>(ln_b + d4);

  for (int t = 0; t < 32; ++t) {
    const int s = c * 32 + t;
    const float4 hd = *reinterpret_cast<const float4*>(base + (size_t)t * (2 * D_) + d4);
    const float4 gt = *reinterpret_cast<const float4*>(base + (size_t)t * (2 * D_) + D_ + d4);
    GRU_NC(hd.x, gt.x, h0); GRU_NC(hd.y, gt.y, h1);
    GRU_NC(hd.z, gt.z, h2); GRU_NC(hd.w, gt.w, h3);

    float sm = h0 + h1 + h2 + h3;
#pragma unroll
    for (int m = 1; m < 64; m <<= 1) sm += __shfl_xor(sm, m);
    __syncthreads();
    if (l == 0) red[w] = sm;
    __syncthreads();
    const float mu = (red[0] + red[1] + red[2] + red[3]) * (1.f / (float)D_);
    float q = (h0 - mu) * (h0 - mu) + (h1 - mu) * (h1 - mu) +
              (h2 - mu) * (h2 - mu) + (h3 - mu) * (h3 - mu);
#pragma unroll
    for (int m = 1; m < 64; m <<= 1) q += __shfl_xor(q, m);
    __syncthreads();
    if (l == 0) red[w] = q;
    __syncthreads();
    const float var = (red[0] + red[1] + red[2] + red[3]) * (1.f / (float)D_);
    const float rstd = rsqrtf(var + 1e-5f);

    const int tok = X[b * S_ + s];
    const float4 e = *reinterpret_cast<const float4*>(emb + (size_t)tok * D_ + d4);
    const float x0 = (h0 - mu) * rstd * lg.x + lb.x + e.x;
    const float x1 = (h1 - mu) * rstd * lg.y + lb.y + e.y;
    const float x2 = (h2 - mu) * rstd * lg.z + lb.z + e.z;
    const float x3 = (h3 - mu) * rstd * lg.w + lb.w + e.w;
    const u64 pk = pack4bf(x0, x1, x2, x3);

    const size_t row = (size_t)b * S_ + s;
    *(u64*)(&Aconv[row * 3072 + D_ + d4]) = pk;
    if (s + 1 < S_) *(u64*)(&Aconv[(row + 1) * 3072 + d4]) = pk;
    if (s > 0)      *(u64*)(&Aconv[(row - 1) * 3072 + 2 * D_ + d4]) = pk;
    if (s == 0)       *(u64*)(&Aconv[row * 3072 + d4]) = 0ull;
    if (s == S_ - 1)  *(u64*)(&Aconv[row * 3072 + 2 * D_ + d4]) = 0ull;
  }
}

// ---------------------------------------------------------------------------
// BatchNorm
// ---------------------------------------------------------------------------
__global__ __launch_bounds__(256) void bn_partial(
    const float* __restrict__ cv, float* __restrict__ ps, float* __restrict__ pq)
{
  const int blk = blockIdx.x;
  const int c4 = threadIdx.x * 4;
  float s0 = 0, s1 = 0, s2 = 0, s3 = 0, q0 = 0, q1 = 0, q2 = 0, q3 = 0;
  for (int r = 0; r < 64; ++r) {
    const float4 v = *reinterpret_cast<const float4*>(cv + ((size_t)blk * 64 + r) * D_ + c4);
    s0 += v.x; s1 += v.y; s2 += v.z; s3 += v.w;
    q0 += v.x * v.x; q1 += v.y * v.y; q2 += v.z * v.z; q3 += v.w * v.w;
  }
  *(float4*)(ps + (size_t)blk * D_ + c4) = make_float4(s0, s1, s2, s3);
  *(float4*)(pq + (size_t)blk * D_ + c4) = make_float4(q0, q1, q2, q3);
}

__global__ void bn_finalize(const float* __restrict__ ps, const float* __restrict__ pq,
                            const float* __restrict__ bn_g, const float* __restrict__ bn_b,
                            float* __restrict__ scale, float* __restrict__ shift)
{
  const int c = blockIdx.x * 256 + threadIdx.x;
  float s = 0.f, q = 0.f;
  for (int blk = 0; blk < 64; ++blk) { s += ps[(size_t)blk * D_ + c]; q += pq[(size_t)blk * D_ + c]; }
  const float m = s * (1.f / (float)BS_);
  const float var = q * (1.f / (float)BS_) - m * m;
  const float rs = rsqrtf(var + 1e-5f);
  const float sc = bn_g[c] * rs;
  scale[c] = sc;
  shift[c] = bn_b[c] - m * sc;
}

__global__ __launch_bounds__(256) void bn_apply(
    const float* __restrict__ cv, const float* __restrict__ scale,
    const float* __restrict__ shift, u16* __restrict__ out)
{
  const size_t idx = ((size_t)blockIdx.x * 256 + threadIdx.x) * 4;
  const int c = (int)(idx & 1023);
  const float4 v = *reinterpret_cast<const float4*>(cv + idx);
  const float4 sc = *reinterpret_cast<const float4*>(scale + c);
  const float4 sh = *reinterpret_cast<const float4*>(shift + c);
  *(u64*)(&out[idx]) = pack4bf(v.x * sc.x + sh.x, v.y * sc.y + sh.y,
                               v.z * sc.z + sh.z, v.w * sc.w + sh.w);
}

// ---------------------------------------------------------------------------
extern "C" void kernel_launch(void* const* d_in, const int* in_sizes, int n_in,
                              void* d_out, int out_size, void* d_ws, size_t ws_size,
                              hipStream_t stream)
{
  const int*   X      = (const int*)d_in[0];
  const float* emb    = (const float*)d_in[1];
  const float* w_hg   = (const float*)d_in[2];
  const float* conv_w = (const float*)d_in[3];
  // d_in[4] = conv_b: exactly cancelled by training-mode BN (mean-subtract)
  const float* bn_g   = (const float*)d_in[5];
  const float* bn_b   = (const float*)d_in[6];
  const float* ln_g   = (const float*)d_in[7];
  const float* ln_b   = (const float*)d_in[8];
  const float* w1     = (const float*)d_in[9];
  const float* b1     = (const float*)d_in[10];
  const float* w2     = (const float*)d_in[11];
  const float* b2     = (const float*)d_in[12];
  const float* w3     = (const float*)d_in[13];
  const float* b3     = (const float*)d_in[14];
  float* out = (float*)d_out;
  char* ws = (char*)d_ws;

  const size_t OFF_A4    = 0;
  const size_t BASE      = 16777216;
  const size_t OFF_W3T   = BASE;
  const size_t OFF_WHGT  = BASE;
  const size_t OFF_W1T   = BASE + 4194304;
  const size_t OFF_W2T   = OFF_W1T + 4194304;
  const size_t OFF_WCVT  = OFF_W2T + 8388608;
  const size_t OFF_XBF   = OFF_WCVT + 6291456;
  const size_t OFF_HG    = OFF_XBF + 8388608;
  const size_t OFF_CB    = OFF_HG + 33554432;
  const size_t OFF_VB    = OFF_CB + 524288;
  const size_t OFF_HS    = OFF_VB + 524288;
  const size_t OFF_ACONV = OFF_HS + 524288;
  const size_t OFF_CVO   = OFF_ACONV + 25165824;
  const size_t OFF_A2    = OFF_CVO + 16777216;
  const size_t OFF_A3    = OFF_A2 + 8388608;
  const size_t OFF_BNS   = OFF_A3 + 16777216;
  const size_t OFF_BNQ   = OFF_BNS + 262144;
  const size_t OFF_SC    = OFF_BNQ + 262144;
  const size_t OFF_SH    = OFF_SC + 4096;
  (void)in_sizes; (void)n_in; (void)out_size; (void)ws_size;

  u16*   WHGT = (u16*)(ws + OFF_WHGT);
  u16*   W1T  = (u16*)(ws + OFF_W1T);
  u16*   W2T  = (u16*)(ws + OFF_W2T);
  u16*   W3T  = (u16*)(ws + OFF_W3T);
  u16*   WCVT = (u16*)(ws + OFF_WCVT);
  u16*   XBF  = (u16*)(ws + OFF_XBF);
  float* HG   = (float*)(ws + OFF_HG);
  float* CB   = (float*)(ws + OFF_CB);
  float* VB   = (float*)(ws + OFF_VB);
  float* HS   = (float*)(ws + OFF_HS);
  u16*   ACONV= (u16*)(ws + OFF_ACONV);
  float* CVO  = (float*)(ws + OFF_CVO);
  u16*   A2   = (u16*)(ws + OFF_A2);
  u16*   A3   = (u16*)(ws + OFF_A3);
  u16*   A4   = (u16*)(ws + OFF_A4);
  float* BNS  = (float*)(ws + OFF_BNS);
  float* BNQ  = (float*)(ws + OFF_BNQ);
  float* SC   = (float*)(ws + OFF_SC);
  float* SH   = (float*)(ws + OFF_SH);

  transpose_f2b<<<dim3(2048 / 32, 1024 / 32), 256, 0, stream>>>(w_hg, WHGT, 1024, 2048);
  transpose_f2b<<<dim3(2048 / 32, 1024 / 32), 256, 0, stream>>>(w1,   W1T,  1024, 2048);
  transpose_f2b<<<dim3(2048 / 32, 2048 / 32), 256, 0, stream>>>(w2,   W2T,  2048, 2048);
  convw_reorder<<<4096, 256, 0, stream>>>(conv_w, WCVT);

  gather_emb<<<BS_, 256, 0, stream>>>(X, emb, XBF);

  gemm_bt<false, false, false><<<dim3(2048 / 128, BS_ / 128), 256, 0, stream>>>(
      XBF, WHGT, nullptr, HG, BS_, 2048, 1024);

  scan_partial<<<B_ * 64, 256, 0, stream>>>(HG, CB, VB);
  scan_carry<<<8, 256, 0, stream>>>(CB, VB, HS);
  scan_emit<<<B_ * 64, 256, 0, stream>>>(HG, HS, X, emb, ln_g, ln_b, ACONV);

  gemm_bt<false, false, false><<<dim3(1024 / 128, BS_ / 128), 256, 0, stream>>>(
      ACONV, WCVT, nullptr, CVO, BS_, 1024, 3072);

  bn_partial<<<64, 256, 0, stream>>>(CVO, BNS, BNQ);
  bn_finalize<<<4, 256, 0, stream>>>(BNS, BNQ, bn_g, bn_b, SC, SH);
  bn_apply<<<4096, 256, 0, stream>>>(CVO, SC, SH, A2);

  gemm_bt<true, true, true><<<dim3(2048 / 128, BS_ / 128), 256, 0, stream>>>(
      A2, W1T, b1, A3, BS_, 2048, 1024);
  gemm_bt<true, true, true><<<dim3(2048 / 128, BS_ / 128), 256, 0, stream>>>(
      A3, W2T, b2, A4, BS_, 2048, 2048);

  transpose_f2b<<<dim3(V_ / 32, 2048 / 32), 256, 0, stream>>>(w3, W3T, 2048, V_);
  // 256^2 8-phase GEMM, chunk-rasterized: 16 m-tiles x 125 n-tiles, CW=16
  gemm256_bt<false, false, true><<<dim3((BS_ / 256) * (V_ / 256)), 512, 0, stream>>>(
      A4, W3T, b3, out, BS_, V_, 2048, 16);
}

// Round 3
// 891.164 us; speedup vs baseline: 1.3504x; 1.0456x over previous
//
#include <hip/hip_runtime.h>
#include <hip/hip_bf16.h>

// Problem constants
#define B_  2
#define S_  2048
#define D_  1024
#define V_  32000
#define BS_ 4096          // B*S rows

typedef __attribute__((ext_vector_type(4))) float f32x4;
typedef __attribute__((ext_vector_type(8))) short short8;
typedef unsigned long long u64;
typedef unsigned short u16;

__device__ __forceinline__ u16 f2bf(float x) {           // RNE f32->bf16
  unsigned int u = __float_as_uint(x);
  u += 0x7FFFu + ((u >> 16) & 1u);
  return (u16)(u >> 16);
}
__device__ __forceinline__ u64 pack4bf(float a, float b, float c, float d) {
  return (u64)f2bf(a) | ((u64)f2bf(b) << 16) | ((u64)f2bf(c) << 32) | ((u64)f2bf(d) << 48);
}

#define GLOAD_LDS16(g, l) __builtin_amdgcn_global_load_lds( \
    (const __attribute__((address_space(1))) void*)(g),     \
    (__attribute__((address_space(3))) void*)(l), 16, 0, 0)

// LDS byte address (32-bit) of a __shared__ object
__device__ __forceinline__ unsigned lds_addr32(const void* p) {
  return (unsigned)(uintptr_t)(const __attribute__((address_space(3))) void*)p;
}
// opaque ds_read_b128: compiler cannot see the LDS alias nor insert vmcnt
__device__ __forceinline__ short8 ds_read128(unsigned a) {
  short8 r;
  asm volatile("ds_read_b128 %0, %1" : "=&v"(r) : "v"(a));
  return r;
}

// ---------------------------------------------------------------------------
// 128x128 m97-structure GEMM (kept for the small GEMMs)
// ---------------------------------------------------------------------------
template<bool RELU, bool BF16OUT, bool HASBIAS>
__global__ __launch_bounds__(256) void gemm_bt(
    const u16* __restrict__ A, const u16* __restrict__ Bt,
    const float* __restrict__ bias, void* __restrict__ Cout,
    int M, int N, int K)
{
  __shared__ __attribute__((aligned(16))) u16 Alds[128 * 64];
  __shared__ __attribute__((aligned(16))) u16 Blds[128 * 64];
  const int tid = threadIdx.x;
  const int w = tid >> 6, l = tid & 63;
  const int wr = w >> 1, wc = w & 1;
  const int m0 = blockIdx.y * 128, n0 = blockIdx.x * 128;
  const int lr = l >> 3, lc = l & 7;
  const int fr = l & 15, fq = l >> 4;

  const u16* Ag = A + (size_t)(m0 + w * 8 + lr) * K + lc * 8;
  const u16* Bg = Bt + (size_t)(n0 + w * 8 + lr) * K + lc * 8;

  f32x4 acc[4][4];
#pragma unroll
  for (int i = 0; i < 4; ++i)
#pragma unroll
    for (int j = 0; j < 4; ++j) acc[i][j] = {0.f, 0.f, 0.f, 0.f};

  for (int kt = 0; kt < K; kt += 64) {
#pragma unroll
    for (int r = 0; r < 4; ++r) {
      GLOAD_LDS16(Ag + (size_t)(r * 32) * K + kt, &Alds[(r * 32 + w * 8) * 64]);
      GLOAD_LDS16(Bg + (size_t)(r * 32) * K + kt, &Blds[(r * 32 + w * 8) * 64]);
    }
    __syncthreads();
#pragma unroll
    for (int ks = 0; ks < 2; ++ks) {
      short8 af[4], bfv[4];
#pragma unroll
      for (int i = 0; i < 4; ++i)
        af[i] = *reinterpret_cast<const short8*>(
            &Alds[(wr * 64 + i * 16 + fr) * 64 + ks * 32 + fq * 8]);
#pragma unroll
      for (int j = 0; j < 4; ++j)
        bfv[j] = *reinterpret_cast<const short8*>(
            &Blds[(wc * 64 + j * 16 + fr) * 64 + ks * 32 + fq * 8]);
#pragma unroll
      for (int i = 0; i < 4; ++i)
#pragma unroll
        for (int j = 0; j < 4; ++j)
          acc[i][j] = __builtin_amdgcn_mfma_f32_16x16x32_bf16(af[i], bfv[j], acc[i][j], 0, 0, 0);
    }
    __syncthreads();
  }

  const int row0 = m0 + wr * 64 + fq * 4;
  const int col0 = n0 + wc * 64 + fr;
#pragma unroll
  for (int j = 0; j < 4; ++j) {
    const int col = col0 + j * 16;
    const float bv = HASBIAS ? bias[col] : 0.f;
#pragma unroll
    for (int i = 0; i < 4; ++i) {
#pragma unroll
      for (int r = 0; r < 4; ++r) {
        const int row = row0 + i * 16 + r;
        float v = acc[i][j][r] + bv;
        if (RELU) v = fmaxf(v, 0.f);
        if (BF16OUT) ((u16*)Cout)[(size_t)row * N + col] = f2bf(v);
        else         ((float*)Cout)[(size_t)row * N + col] = v;
      }
    }
  }
}

// ---------------------------------------------------------------------------
// 256x256 8-phase GEMM (T2 swizzle + T3/T4 counted-vmcnt + T5 setprio).
// 512 thr = 8 waves (2M x 4N); BK=64; LDS 128KB dbuf; 4 phases/K-tile.
// Template-exact barriers (bare s_barrier); asm ds_read so the compiler
// cannot insert conservative vmcnt before fragment reads (rule #18 fences).
// ---------------------------------------------------------------------------
#define AOFF(b, h) (((b) * 4 + (h)) * 8192)
#define BOFF(b, h) (((b) * 4 + 2 + (h)) * 8192)
#define BARRIER() __builtin_amdgcn_s_barrier()
#define WAITL0_PIN() do { asm volatile("s_waitcnt lgkmcnt(0)" ::: "memory"); \
                          __builtin_amdgcn_sched_barrier(0); } while (0)

template<bool RELU, bool BF16OUT, bool HASBIAS>
__global__ __launch_bounds__(512, 2) void gemm256_bt(
    const u16* __restrict__ A, const u16* __restrict__ Bt,
    const float* __restrict__ bias, void* __restrict__ Cout,
    int M, int N, int K, int CW)
{
  __shared__ __attribute__((aligned(16))) u16 LDS[65536];
  const int tid = threadIdx.x;
  const int w = tid >> 6, l = tid & 63;
  const int wr = w >> 2, wc = w & 3;          // 2 x 4 wave grid; wave owns 128x64
  const int fr = l & 15, fq = l >> 4;
  const unsigned ldsb = lds_addr32(&LDS[0]);

  // chunk rasterization: CW n-tiles x all m-tiles per chunk (m fastest)
  const int MTt = M >> 8;
  const int bpc = MTt * CW;
  const int chunk = blockIdx.x / bpc, rem = blockIdx.x % bpc;
  const int m0 = (rem % MTt) << 8;
  const int n0 = ((chunk * CW) + rem / MTt) << 8;

  const int NT = K >> 6;
  const u16* Abase = A + (size_t)m0 * K;
  const u16* Bbase = Bt + (size_t)n0 * K;

  // staging lane geometry: granule G = w*128 + q*64 + l, row r = G>>3,
  // src granule g = (l&7) ^ (r&7)  [XOR swizzle, both sides]
  const int rq_[2] = { w * 16 + (l >> 3), w * 16 + 8 + (l >> 3) };
  const int gq_[2] = { (l & 7) ^ (rq_[0] & 7), (l & 7) ^ (rq_[1] & 7) };

#define STAGE_HALF(matbase, h, t, ldsoff) do {                               \
  _Pragma("unroll")                                                          \
  for (int q_ = 0; q_ < 2; ++q_)                                             \
    GLOAD_LDS16((matbase) + ((size_t)((h) * 128 + rq_[q_])) * K +            \
                    (size_t)(t) * 64 + gq_[q_] * 8,                          \
                &LDS[(ldsoff) + (w * 128 + q_ * 64) * 8]);                   \
} while (0)

#define READ_A(arr, bufb, q_) do {                                           \
  _Pragma("unroll")                                                          \
  for (int i_ = 0; i_ < 4; ++i_) {                                           \
    const int r_ = (q_) * 64 + i_ * 16 + fr;                                 \
    _Pragma("unroll")                                                        \
    for (int ks_ = 0; ks_ < 2; ++ks_)                                        \
      arr[i_][ks_] = ds_read128(ldsb + 2u * (unsigned)(AOFF(bufb, wr) +      \
          r_ * 64 + ((ks_ * 4 + fq) ^ (fr & 7)) * 8));                       \
  } } while (0)

#define READ_B(arr, bufb, jq_) do {                                          \
  _Pragma("unroll")                                                          \
  for (int j_ = 0; j_ < 2; ++j_) {                                           \
    const int r_ = (wc & 1) * 64 + (jq_) * 32 + j_ * 16 + fr;                \
    _Pragma("unroll")                                                        \
    for (int ks_ = 0; ks_ < 2; ++ks_)                                        \
      arr[j_][ks_] = ds_read128(ldsb + 2u * (unsigned)(BOFF(bufb, wc >> 1) + \
          r_ * 64 + ((ks_ * 4 + fq) ^ (fr & 7)) * 8));                       \
  } } while (0)

#define MFMA_Q(arrA, arrB, itb, jtb) do {                                    \
  _Pragma("unroll")                                                          \
  for (int i_ = 0; i_ < 4; ++i_)                                             \
    _Pragma("unroll")                                                        \
    for (int j_ = 0; j_ < 2; ++j_)                                           \
      _Pragma("unroll")                                                      \
      for (int ks_ = 0; ks_ < 2; ++ks_)                                      \
        acc[(itb) + i_][(jtb) + j_] = __builtin_amdgcn_mfma_f32_16x16x32_bf16( \
            arrA[i_][ks_], arrB[j_][ks_], acc[(itb) + i_][(jtb) + j_], 0, 0, 0); \
} while (0)

  f32x4 acc[8][4];
#pragma unroll
  for (int i = 0; i < 8; ++i)
#pragma unroll
    for (int j = 0; j < 4; ++j) acc[i][j] = {0.f, 0.f, 0.f, 0.f};

  // prologue: full tile 0, then BH0(1), AH0(1)
  STAGE_HALF(Abase, 0, 0, AOFF(0, 0));
  STAGE_HALF(Abase, 1, 0, AOFF(0, 1));
  STAGE_HALF(Bbase, 0, 0, BOFF(0, 0));
  STAGE_HALF(Bbase, 1, 0, BOFF(0, 1));
  if (NT > 1) {
    STAGE_HALF(Bbase, 0, 1, BOFF(1, 0));
    STAGE_HALF(Abase, 0, 1, AOFF(1, 0));
    asm volatile("s_waitcnt vmcnt(4)" ::: "memory");
  } else {
    asm volatile("s_waitcnt vmcnt(0)" ::: "memory");
  }
  BARRIER();

  for (int t = 0; t < NT; ++t) {
    const int cb = t & 1, nb = cb ^ 1;
    short8 a0[4][2], a1[4][2], b0[2][2], b1[2][2];

    // P1: read a0,b0 (12 ds_read); stage AH1(t+1); MFMA quad (0,0)
    READ_A(a0, cb, 0);
    READ_B(b0, cb, 0);
    if (t + 1 < NT) STAGE_HALF(Abase, 1, t + 1, AOFF(nb, 1));
    BARRIER(); WAITL0_PIN();
    __builtin_amdgcn_s_setprio(1);
    MFMA_Q(a0, b0, 0, 0);
    __builtin_amdgcn_s_setprio(0);
    BARRIER();

    // P2: read b1 (4); stage BH1(t+1); quad (0,2)
    READ_B(b1, cb, 1);
    if (t + 1 < NT) STAGE_HALF(Bbase, 1, t + 1, BOFF(nb, 1));
    BARRIER(); WAITL0_PIN();
    __builtin_amdgcn_s_setprio(1);
    MFMA_Q(a0, b1, 0, 2);
    __builtin_amdgcn_s_setprio(0);
    BARRIER();

    // P3: read a1 (8); stage BH0(t+2); quad (4,2)
    READ_A(a1, cb, 1);
    if (t + 2 < NT) STAGE_HALF(Bbase, 0, t + 2, BOFF(cb, 0));
    BARRIER(); WAITL0_PIN();
    __builtin_amdgcn_s_setprio(1);
    MFMA_Q(a1, b1, 4, 2);
    __builtin_amdgcn_s_setprio(0);
    BARRIER();

    // P4: stage AH0(t+2); quad (4,0); counted vmcnt at tile boundary
    if (t + 2 < NT) STAGE_HALF(Abase, 0, t + 2, AOFF(cb, 0));
    BARRIER(); WAITL0_PIN();
    __builtin_amdgcn_s_setprio(1);
    MFMA_Q(a1, b0, 4, 0);
    __builtin_amdgcn_s_setprio(0);
    if (t + 2 < NT) { asm volatile("s_waitcnt vmcnt(4)" ::: "memory"); }
    else            { asm volatile("s_waitcnt vmcnt(0)" ::: "memory"); }
    BARRIER();
  }

  // --- epilogue via wave-private LDS slice -> coalesced dwordx4 stores ---
  // acc layout: col = lane&15, row = (lane>>4)*4 + reg
  float* lf = (float*)(void*)(&LDS[0]) + (size_t)w * 1088;   // 16 rows x 68 pad
  const int row_base = m0 + wr * 128;
  const int col_base = n0 + wc * 64;
  float bvv[4];
#pragma unroll
  for (int jt = 0; jt < 4; ++jt)
    bvv[jt] = HASBIAS ? bias[col_base + jt * 16 + fr] : 0.f;
  const int er = l >> 4, ec = (l & 15) * 4;
#pragma unroll
  for (int it = 0; it < 8; ++it) {
#pragma unroll
    for (int jt = 0; jt < 4; ++jt)
#pragma unroll
      for (int rr = 0; rr < 4; ++rr)
        lf[(fq * 4 + rr) * 68 + jt * 16 + fr] = acc[it][jt][rr] + bvv[jt];
    // wave-private: no barrier needed; compiler orders ds_write->ds_read
#pragma unroll
    for (int ch = 0; ch < 4; ++ch) {
      f32x4 vv = *(const f32x4*)&lf[(ch * 4 + er) * 68 + ec];
      if (RELU) {
        vv[0] = fmaxf(vv[0], 0.f); vv[1] = fmaxf(vv[1], 0.f);
        vv[2] = fmaxf(vv[2], 0.f); vv[3] = fmaxf(vv[3], 0.f);
      }
      const int grow = row_base + it * 16 + ch * 4 + er;
      if (BF16OUT) {
        *(u64*)(&((u16*)Cout)[(size_t)grow * N + col_base + ec]) =
            pack4bf(vv[0], vv[1], vv[2], vv[3]);
      } else {
        *(f32x4*)(&((float*)Cout)[(size_t)grow * N + col_base + ec]) = vv;
      }
    }
    __syncthreads();  // keep waves loosely in step; also WAR-protect slices
  }
#undef STAGE_HALF
#undef READ_A
#undef READ_B
#undef MFMA_Q
}

// ---------------------------------------------------------------------------
// Weight prep
// ---------------------------------------------------------------------------
__global__ __launch_bounds__(256) void transpose_f2b(
    const float* __restrict__ in, u16* __restrict__ out, int K, int N)
{
  __shared__ float t[32][33];
  const int n0 = blockIdx.x * 32, k0 = blockIdx.y * 32;
  const int r = threadIdx.x >> 5, cc = threadIdx.x & 31;
#pragma unroll
  for (int rr = 0; rr < 4; ++rr) {
    const int ki = rr * 8 + r;
    t[ki][cc] = in[(size_t)(k0 + ki) * N + n0 + cc];
  }
  __syncthreads();
#pragma unroll
  for (int rr = 0; rr < 4; ++rr) {
    const int ni = rr * 8 + r;
    out[(size_t)(n0 + ni) * K + k0 + cc] = f2bf(t[cc][ni]);
  }
}

__global__ __launch_bounds__(256) void convw_reorder(
    const float* __restrict__ cw, u16* __restrict__ out)
{
  const int gid = blockIdx.x * 256 + threadIdx.x;   // o*D + i
  const int o = gid >> 10, i = gid & 1023;
  const float w0 = cw[(size_t)gid * 3 + 0];
  const float w1 = cw[(size_t)gid * 3 + 1];
  const float w2 = cw[(size_t)gid * 3 + 2];
  out[(size_t)o * 3072 + i]          = f2bf(w0);
  out[(size_t)o * 3072 + 1024 + i]   = f2bf(w1);
  out[(size_t)o * 3072 + 2048 + i]   = f2bf(w2);
}

__global__ __launch_bounds__(256) void gather_emb(
    const int* __restrict__ X, const float* __restrict__ emb, u16* __restrict__ xb)
{
  const int row = blockIdx.x;
  const int tok = X[row];
  const int d4 = threadIdx.x * 4;
  const float4 v = *reinterpret_cast<const float4*>(emb + (size_t)tok * D_ + d4);
  *(u64*)(&xb[(size_t)row * D_ + d4]) = pack4bf(v.x, v.y, v.z, v.w);
}

// ---------------------------------------------------------------------------
// minGRU scan (3-pass chunked linear recurrence)
// ---------------------------------------------------------------------------
#define GRU_CP(hid_, gate_, h_, cp_) {                                   \
  const float t_ = __expf(-(gate_));                                     \
  const float z_ = 1.f / (1.f + t_);                                     \
  const float c_ = t_ * z_;                                              \
  const float g_ = ((hid_) >= 0.f) ? ((hid_) + 0.5f)                     \
                                   : (1.f / (1.f + __expf(-(hid_))));    \
  (h_) = c_ * (h_) + z_ * g_; (cp_) *= c_; }

#define GRU_NC(hid_, gate_, h_) {                                        \
  const float t_ = __expf(-(gate_));                                     \
  const float z_ = 1.f / (1.f + t_);                                     \
  const float g_ = ((hid_) >= 0.f) ? ((hid_) + 0.5f)                     \
                                   : (1.f / (1.f + __expf(-(hid_))));    \
  (h_) = (t_ * z_) * (h_) + z_ * g_; }

__global__ __launch_bounds__(256) void scan_partial(
    const float* __restrict__ hg, float* __restrict__ Cb, float* __restrict__ Vb)
{
  const int b = blockIdx.x >> 6, c = blockIdx.x & 63;
  const int d4 = threadIdx.x * 4;
  const float* base = hg + ((size_t)b * S_ + (size_t)c * 32) * (2 * D_);
  float h[4] = {0.f, 0.f, 0.f, 0.f}, cp[4] = {1.f, 1.f, 1.f, 1.f};
  for (int t = 0; t < 32; ++t) {
    const float4 hd = *reinterpret_cast<const float4*>(base + (size_t)t * (2 * D_) + d4);
    const float4 gt = *reinterpret_cast<const float4*>(base + (size_t)t * (2 * D_) + D_ + d4);
    GRU_CP(hd.x, gt.x, h[0], cp[0]); GRU_CP(hd.y, gt.y, h[1], cp[1]);
    GRU_CP(hd.z, gt.z, h[2], cp[2]); GRU_CP(hd.w, gt.w, h[3], cp[3]);
  }
  const size_t o = ((size_t)(b * 64 + c)) * D_ + d4;
  *(float4*)(Cb + o) = make_float4(cp[0], cp[1], cp[2], cp[3]);
  *(float4*)(Vb + o) = make_float4(h[0], h[1], h[2], h[3]);
}

__global__ void scan_carry(const float* __restrict__ Cb, const float* __restrict__ Vb,
                           float* __restrict__ Hs)
{
  const int gid = blockIdx.x * 256 + threadIdx.x;   // 0..2047 = (b,d)
  const int b = gid >> 10, d = gid & 1023;
  float h = 0.f;
  for (int c = 0; c < 64; ++c) {
    const size_t o = ((size_t)(b * 64 + c)) * D_ + d;
    Hs[o] = h;
    h = Cb[o] * h + Vb[o];
  }
}

__global__ __launch_bounds__(256) void scan_emit(
    const float* __restrict__ hg, const float* __restrict__ Hs,
    const int* __restrict__ X, const float* __restrict__ emb,
    const float* __restrict__ ln_g, const float* __restrict__ ln_b,
    u16* __restrict__ Aconv)
{
  __shared__ float red[4];
  const int b = blockIdx.x >> 6, c = blockIdx.x & 63;
  const int tid = threadIdx.x;
  const int w = tid >> 6, l = tid & 63;
  const int d4 = tid * 4;
  const float* base = hg + ((size_t)b * S_ + (size_t)c * 32) * (2 * D_);
  float h0, h1, h2, h3;
  {
    const float4 hs = *reinterpret_cast<const float4*>(Hs + ((size_t)(b * 64 + c)) * D_ + d4);
    h0 = hs.x; h1 = hs.y; h2 = hs.z; h3 = hs.w;
  }
  const float4 lg = *reinterpret_cast<const float4*>(ln_g + d4);
  const float4 lb = *reinterpret_cast<const float4*>(ln_b + d4);

  for (int t = 0; t < 32; ++t) {
    const int s = c * 32 + t;
    const float4 hd = *reinterpret_cast<const float4*>(base + (size_t)t * (2 * D_) + d4);
    const float4 gt = *reinterpret_cast<const float4*>(base + (size_t)t * (2 * D_) + D_ + d4);
    GRU_NC(hd.x, gt.x, h0); GRU_NC(hd.y, gt.y, h1);
    GRU_NC(hd.z, gt.z, h2); GRU_NC(hd.w, gt.w, h3);

    float sm = h0 + h1 + h2 + h3;
#pragma unroll
    for (int m = 1; m < 64; m <<= 1) sm += __shfl_xor(sm, m);
    __syncthreads();
    if (l == 0) red[w] = sm;
    __syncthreads();
    const float mu = (red[0] + red[1] + red[2] + red[3]) * (1.f / (float)D_);
    float q = (h0 - mu) * (h0 - mu) + (h1 - mu) * (h1 - mu) +
              (h2 - mu) * (h2 - mu) + (h3 - mu) * (h3 - mu);
#pragma unroll
    for (int m = 1; m < 64; m <<= 1) q += __shfl_xor(q, m);
    __syncthreads();
    if (l == 0) red[w] = q;
    __syncthreads();
    const float var = (red[0] + red[1] + red[2] + red[3]) * (1.f / (float)D_);
    const float rstd = rsqrtf(var + 1e-5f);

    const int tok = X[b * S_ + s];
    const float4 e = *reinterpret_cast<const float4*>(emb + (size_t)tok * D_ + d4);
    const float x0 = (h0 - mu) * rstd * lg.x + lb.x + e.x;
    const float x1 = (h1 - mu) * rstd * lg.y + lb.y + e.y;
    const float x2 = (h2 - mu) * rstd * lg.z + lb.z + e.z;
    const float x3 = (h3 - mu) * rstd * lg.w + lb.w + e.w;
    const u64 pk = pack4bf(x0, x1, x2, x3);

    const size_t row = (size_t)b * S_ + s;
    *(u64*)(&Aconv[row * 3072 + D_ + d4]) = pk;
    if (s + 1 < S_) *(u64*)(&Aconv[(row + 1) * 3072 + d4]) = pk;
    if (s > 0)      *(u64*)(&Aconv[(row - 1) * 3072 + 2 * D_ + d4]) = pk;
    if (s == 0)       *(u64*)(&Aconv[row * 3072 + d4]) = 0ull;
    if (s == S_ - 1)  *(u64*)(&Aconv[row * 3072 + 2 * D_ + d4]) = 0ull;
  }
}

// ---------------------------------------------------------------------------
// BatchNorm
// ---------------------------------------------------------------------------
__global__ __launch_bounds__(256) void bn_partial(
    const float* __restrict__ cv, float* __restrict__ ps, float* __restrict__ pq)
{
  const int blk = blockIdx.x;
  const int c4 = threadIdx.x * 4;
  float s0 = 0, s1 = 0, s2 = 0, s3 = 0, q0 = 0, q1 = 0, q2 = 0, q3 = 0;
  for (int r = 0; r < 64; ++r) {
    const float4 v = *reinterpret_cast<const float4*>(cv + ((size_t)blk * 64 + r) * D_ + c4);
    s0 += v.x; s1 += v.y; s2 += v.z; s3 += v.w;
    q0 += v.x * v.x; q1 += v.y * v.y; q2 += v.z * v.z; q3 += v.w * v.w;
  }
  *(float4*)(ps + (size_t)blk * D_ + c4) = make_float4(s0, s1, s2, s3);
  *(float4*)(pq + (size_t)blk * D_ + c4) = make_float4(q0, q1, q2, q3);
}

__global__ void bn_finalize(const float* __restrict__ ps, const float* __restrict__ pq,
                            const float* __restrict__ bn_g, const float* __restrict__ bn_b,
                            float* __restrict__ scale, float* __restrict__ shift)
{
  const int c = blockIdx.x * 256 + threadIdx.x;
  float s = 0.f, q = 0.f;
  for (int blk = 0; blk < 64; ++blk) { s += ps[(size_t)blk * D_ + c]; q += pq[(size_t)blk * D_ + c]; }
  const float m = s * (1.f / (float)BS_);
  const float var = q * (1.f / (float)BS_) - m * m;
  const float rs = rsqrtf(var + 1e-5f);
  const float sc = bn_g[c] * rs;
  scale[c] = sc;
  shift[c] = bn_b[c] - m * sc;
}

__global__ __launch_bounds__(256) void bn_apply(
    const float* __restrict__ cv, const float* __restrict__ scale,
    const float* __restrict__ shift, u16* __restrict__ out)
{
  const size_t idx = ((size_t)blockIdx.x * 256 + threadIdx.x) * 4;
  const int c = (int)(idx & 1023);
  const float4 v = *reinterpret_cast<const float4*>(cv + idx);
  const float4 sc = *reinterpret_cast<const float4*>(scale + c);
  const float4 sh = *reinterpret_cast<const float4*>(shift + c);
  *(u64*)(&out[idx]) = pack4bf(v.x * sc.x + sh.x, v.y * sc.y + sh.y,
                               v.z * sc.z + sh.z, v.w * sc.w + sh.w);
}

// ---------------------------------------------------------------------------
extern "C" void kernel_launch(void* const* d_in, const int* in_sizes, int n_in,
                              void* d_out, int out_size, void* d_ws, size_t ws_size,
                              hipStream_t stream)
{
  const int*   X      = (const int*)d_in[0];
  const float* emb    = (const float*)d_in[1];
  const float* w_hg   = (const float*)d_in[2];
  const float* conv_w = (const float*)d_in[3];
  // d_in[4] = conv_b: exactly cancelled by training-mode BN (mean-subtract)
  const float* bn_g   = (const float*)d_in[5];
  const float* bn_b   = (const float*)d_in[6];
  const float* ln_g   = (const float*)d_in[7];
  const float* ln_b   = (const float*)d_in[8];
  const float* w1     = (const float*)d_in[9];
  const float* b1     = (const float*)d_in[10];
  const float* w2     = (const float*)d_in[11];
  const float* b2     = (const float*)d_in[12];
  const float* w3     = (const float*)d_in[13];
  const float* b3     = (const float*)d_in[14];
  float* out = (float*)d_out;
  char* ws = (char*)d_ws;

  const size_t OFF_A4    = 0;
  const size_t BASE      = 16777216;
  const size_t OFF_W3T   = BASE;
  const size_t OFF_WHGT  = BASE;
  const size_t OFF_W1T   = BASE + 4194304;
  const size_t OFF_W2T   = OFF_W1T + 4194304;
  const size_t OFF_WCVT  = OFF_W2T + 8388608;
  const size_t OFF_XBF   = OFF_WCVT + 6291456;
  const size_t OFF_HG    = OFF_XBF + 8388608;
  const size_t OFF_CB    = OFF_HG + 33554432;
  const size_t OFF_VB    = OFF_CB + 524288;
  const size_t OFF_HS    = OFF_VB + 524288;
  const size_t OFF_ACONV = OFF_HS + 524288;
  const size_t OFF_CVO   = OFF_ACONV + 25165824;
  const size_t OFF_A2    = OFF_CVO + 16777216;
  const size_t OFF_A3    = OFF_A2 + 8388608;
  const size_t OFF_BNS   = OFF_A3 + 16777216;
  const size_t OFF_BNQ   = OFF_BNS + 262144;
  const size_t OFF_SC    = OFF_BNQ + 262144;
  const size_t OFF_SH    = OFF_SC + 4096;
  (void)in_sizes; (void)n_in; (void)out_size; (void)ws_size;

  u16*   WHGT = (u16*)(ws + OFF_WHGT);
  u16*   W1T  = (u16*)(ws + OFF_W1T);
  u16*   W2T  = (u16*)(ws + OFF_W2T);
  u16*   W3T  = (u16*)(ws + OFF_W3T);
  u16*   WCVT = (u16*)(ws + OFF_WCVT);
  u16*   XBF  = (u16*)(ws + OFF_XBF);
  float* HG   = (float*)(ws + OFF_HG);
  float* CB   = (float*)(ws + OFF_CB);
  float* VB   = (float*)(ws + OFF_VB);
  float* HS   = (float*)(ws + OFF_HS);
  u16*   ACONV= (u16*)(ws + OFF_ACONV);
  float* CVO  = (float*)(ws + OFF_CVO);
  u16*   A2   = (u16*)(ws + OFF_A2);
  u16*   A3   = (u16*)(ws + OFF_A3);
  u16*   A4   = (u16*)(ws + OFF_A4);
  float* BNS  = (float*)(ws + OFF_BNS);
  float* BNQ  = (float*)(ws + OFF_BNQ);
  float* SC   = (float*)(ws + OFF_SC);
  float* SH   = (float*)(ws + OFF_SH);

  transpose_f2b<<<dim3(2048 / 32, 1024 / 32), 256, 0, stream>>>(w_hg, WHGT, 1024, 2048);
  transpose_f2b<<<dim3(2048 / 32, 1024 / 32), 256, 0, stream>>>(w1,   W1T,  1024, 2048);
  transpose_f2b<<<dim3(2048 / 32, 2048 / 32), 256, 0, stream>>>(w2,   W2T,  2048, 2048);
  convw_reorder<<<4096, 256, 0, stream>>>(conv_w, WCVT);

  gather_emb<<<BS_, 256, 0, stream>>>(X, emb, XBF);

  gemm_bt<false, false, false><<<dim3(2048 / 128, BS_ / 128), 256, 0, stream>>>(
      XBF, WHGT, nullptr, HG, BS_, 2048, 1024);

  scan_partial<<<B_ * 64, 256, 0, stream>>>(HG, CB, VB);
  scan_carry<<<8, 256, 0, stream>>>(CB, VB, HS);
  scan_emit<<<B_ * 64, 256, 0, stream>>>(HG, HS, X, emb, ln_g, ln_b, ACONV);

  gemm_bt<false, false, false><<<dim3(1024 / 128, BS_ / 128), 256, 0, stream>>>(
      ACONV, WCVT, nullptr, CVO, BS_, 1024, 3072);

  bn_partial<<<64, 256, 0, stream>>>(CVO, BNS, BNQ);
  bn_finalize<<<4, 256, 0, stream>>>(BNS, BNQ, bn_g, bn_b, SC, SH);
  bn_apply<<<4096, 256, 0, stream>>>(CVO, SC, SH, A2);

  gemm_bt<true, true, true><<<dim3(2048 / 128, BS_ / 128), 256, 0, stream>>>(
      A2, W1T, b1, A3, BS_, 2048, 1024);
  gemm_bt<true, true, true><<<dim3(2048 / 128, BS_ / 128), 256, 0, stream>>>(
      A3, W2T, b2, A4, BS_, 2048, 2048);

  transpose_f2b<<<dim3(V_ / 32, 2048 / 32), 256, 0, stream>>>(w3, W3T, 2048, V_);
  // 256^2 8-phase GEMM, chunk-rasterized: 16 m-tiles x 125 n-tiles, CW=16
  gemm256_bt<false, false, true><<<dim3((BS_ / 256) * (V_ / 256)), 512, 0, stream>>>(
      A4, W3T, b3, out, BS_, V_, 2048, 16);
}